// Round 1
// 190.007 us; speedup vs baseline: 1.0107x; 1.0107x over previous
//
#include <hip/hip_runtime.h>
#include <math.h>

// RMAC for x[64][512][32][32] fp32, L=3, OVR=0.4, EPS=1e-6.
// Regions for H=W=32 (14 distinct, global counted twice):
//   r0 : rows[0,32) cols[0,32)                       (weight 2)
//   r1-4 : rows{[0,21),[11,32)} x cols{[0,21),[11,32)}
//   r5-13: rows{[0,16),[8,24),[16,32)} x cols{[0,16),[8,24),[16,32)}
//
// Pool kernel v2: wave-per-tile, register-only (no LDS arrays, no barriers).
// Lane l holds rows {h0,h0+8,h0+16,h0+24} (h0=l>>3) of col group g=l&7
// (cols 4g..4g+3) via 4 coalesced dwordx4 loads. Row-range maxes in-register,
// h-reduction via ds_swizzle xor8/16 + permlane32_swap, column masking
// (only col boundaries 11 and 21 split a 4-col group -> one special col),
// g-reduction via ds_swizzle xor1/2/4. Lane 0 stores 14 region maxes.
// Predicted: pool ~30us -> ~22-24us (HBM-bound, 128 MiB read @ ~5.7 TB/s).

#define B_ 64
#define C_ 512
#define BC 32768            // B_*C_

template<int IMM>
__device__ __forceinline__ float max_swz(float x) {
    // butterfly max with lane^k (k<32) via ds_swizzle bitmode
    int y = __builtin_amdgcn_ds_swizzle(__float_as_int(x), IMM);
    return fmaxf(x, __int_as_float(y));
}
template<int IMM>
__device__ __forceinline__ float swz(float x) {
    return __int_as_float(__builtin_amdgcn_ds_swizzle(__float_as_int(x), IMM));
}
__device__ __forceinline__ float max_x32(float x) {
    // butterfly max with lane^32 in one VALU pair via v_permlane32_swap
#if __has_builtin(__builtin_amdgcn_permlane32_swap)
    auto r = __builtin_amdgcn_permlane32_swap(__float_as_int(x), __float_as_int(x),
                                              false, false);
    return fmaxf(__int_as_float((int)r[0]), __int_as_float((int)r[1]));
#else
    return fmaxf(x, __shfl_xor(x, 32, 64));
#endif
}

#define SWZ_X1  0x041F
#define SWZ_X2  0x081F
#define SWZ_X4  0x101F
#define SWZ_X8  0x201F
#define SWZ_X16 0x401F

__global__ __launch_bounds__(256) void rmac_pool_kernel(const float* __restrict__ x,
                                                        float* __restrict__ vt) {
    const int lane = threadIdx.x & 63;
    const int tile = (blockIdx.x << 2) | (threadIdx.x >> 6);   // = b*C_ + c
    const float4* __restrict__ xv = (const float4*)(x + ((long long)tile << 10));

    // coalesced: 4 x (64 lanes x 16B) = the whole 4KB tile
    const float4 v0 = xv[lane];          // row h0,     cols 4g..4g+3
    const float4 v1 = xv[lane + 64];     // row h0+8
    const float4 v2 = xv[lane + 128];    // row h0+16
    const float4 v3 = xv[lane + 192];    // row h0+24

    const int h0 = lane >> 3;
    const int g  = lane & 7;
    const float NEG = -INFINITY;

    // per-row max over this lane's 4 columns
    const float gm0 = fmaxf(fmaxf(v0.x, v0.y), fmaxf(v0.z, v0.w));
    const float gm1 = fmaxf(fmaxf(v1.x, v1.y), fmaxf(v1.z, v1.w));
    const float gm2 = fmaxf(fmaxf(v2.x, v2.y), fmaxf(v2.z, v2.w));
    const float gm3 = fmaxf(fmaxf(v3.x, v3.y), fmaxf(v3.z, v3.w));

    // row-range maxes over the lane's rows {h0, h0+8, h0+16, h0+24}
    float a3 = fmaxf(gm0, gm1);                        // rows [0,16)
    float a5 = fmaxf(gm2, gm3);                        // rows [16,32)
    float a0 = fmaxf(a3, a5);                          // rows [0,32)
    float a4 = fmaxf(gm1, gm2);                        // rows [8,24)
    float a1 = fmaxf(a3, (h0 < 5)  ? gm2 : NEG);       // rows [0,21):  h0+16<21
    float a2 = fmaxf(a5, (h0 >= 3) ? gm1 : NEG);       // rows [11,32): h0+8>=11

    // special single columns: col 11 = (g2, j3); col 20 = (g5, j0)
    const bool g2sel = (g == 2);
    const float s0 = g2sel ? v0.w : v0.x;
    const float s1 = g2sel ? v1.w : v1.x;
    const float s2 = g2sel ? v2.w : v2.x;
    const float s3 = g2sel ? v3.w : v3.x;
    float sp1 = fmaxf(fmaxf(s0, s1), (h0 < 5)  ? s2 : NEG);   // rows [0,21)
    float sp2 = fmaxf(fmaxf(s2, s3), (h0 >= 3) ? s1 : NEG);   // rows [11,32)

    // ---- reduce over h0 (lane bits 3..5): xor8, xor16, permlane32 ----
#define RH(v) v = max_swz<SWZ_X8>(v); v = max_swz<SWZ_X16>(v); v = max_x32(v);
    RH(a0) RH(a1) RH(a2) RH(a3) RH(a4) RH(a5) RH(sp1) RH(sp2)
#undef RH
    // now lanes 0..7 hold per-column-group row-range maxes A[rr][g]

    // ---- per-lane region partials + reduce over g (lane bits 0..2) ----
    // Only lane 0's final value is stored; shortcuts below are lane-0-exact.
#define RG3(v) v = max_swz<SWZ_X1>(v); v = max_swz<SWZ_X2>(v); v = max_swz<SWZ_X4>(v);

    float p0 = a0;                                      RG3(p0)    // full tile
    float p1 = (g <= 4) ? a1 : ((g == 5) ? sp1 : NEG);  RG3(p1)    // R[0,21) C[0,21)
    float p2 = (g >= 3) ? a1 : (g2sel ? sp1 : NEG);     RG3(p2)    // R[0,21) C[11,32)
    float p3 = (g <= 4) ? a2 : ((g == 5) ? sp2 : NEG);  RG3(p3)    // R[11,32) C[0,21)
    float p4 = (g >= 3) ? a2 : (g2sel ? sp2 : NEG);     RG3(p4)    // R[11,32) C[11,32)

    const bool c4 = (g >= 2) && (g < 6);                // cols [8,24) = groups 2..5
    // C[0,16): groups 0..3 -> xor1+xor2 gives lane0 = max(g0..g3), no mask needed
    float p5  = max_swz<SWZ_X2>(max_swz<SWZ_X1>(a3));
    float p8  = max_swz<SWZ_X2>(max_swz<SWZ_X1>(a4));
    float p11 = max_swz<SWZ_X2>(max_swz<SWZ_X1>(a5));
    // C[8,24): masked full butterfly
    float p6  = c4 ? a3 : NEG;                          RG3(p6)
    float p9  = c4 ? a4 : NEG;                          RG3(p9)
    float p12 = c4 ? a5 : NEG;                          RG3(p12)
    // C[16,32): pre-swizzle xor4 (lane0 sees g4..g7), then xor1+xor2
    float p7  = max_swz<SWZ_X2>(max_swz<SWZ_X1>(swz<SWZ_X4>(a3)));
    float p10 = max_swz<SWZ_X2>(max_swz<SWZ_X1>(swz<SWZ_X4>(a4)));
    float p13 = max_swz<SWZ_X2>(max_swz<SWZ_X1>(swz<SWZ_X4>(a5)));
#undef RG3

    if (lane == 0) {
        float* __restrict__ o = vt + tile;
        o[0 * BC]  = p0;  o[1 * BC]  = p1;  o[2 * BC]  = p2;  o[3 * BC]  = p3;
        o[4 * BC]  = p4;  o[5 * BC]  = p5;  o[6 * BC]  = p6;  o[7 * BC]  = p7;
        o[8 * BC]  = p8;  o[9 * BC]  = p9;  o[10 * BC] = p10; o[11 * BC] = p11;
        o[12 * BC] = p12; o[13 * BC] = p13;
    }
}

__global__ __launch_bounds__(512) void rmac_norm_kernel(const float* __restrict__ vt,
                                                        float* __restrict__ out) {
    const int b = blockIdx.x;
    const int c = threadIdx.x;

    float v[14];
#pragma unroll
    for (int r = 0; r < 14; ++r) v[r] = vt[r * BC + b * C_ + c];

    __shared__ float partial[14][8];
    __shared__ float inv[14];
    const int wid  = c >> 6;
    const int lane = c & 63;

#pragma unroll
    for (int r = 0; r < 14; ++r) {
        float s = v[r] * v[r];
#pragma unroll
        for (int off = 32; off > 0; off >>= 1)
            s += __shfl_down(s, off, 64);
        if (lane == 0) partial[r][wid] = s;
    }
    __syncthreads();

    if (c < 14) {
        float s = 0.f;
#pragma unroll
        for (int wI = 0; wI < 8; ++wI) s += partial[c][wI];
        inv[c] = 1.0f / (sqrtf(s) + 1e-6f);
    }
    __syncthreads();

    float acc = 2.0f * v[0] * inv[0];   // global pool == l=1 region, counted twice
#pragma unroll
    for (int r = 1; r < 14; ++r) acc += v[r] * inv[r];
    out[b * C_ + c] = acc;
}

extern "C" void kernel_launch(void* const* d_in, const int* in_sizes, int n_in,
                              void* d_out, int out_size, void* d_ws, size_t ws_size,
                              hipStream_t stream) {
    const float* x  = (const float*)d_in[0];
    float* out      = (float*)d_out;
    float* vt       = (float*)d_ws;   // 14 * 32768 floats = 1.75 MB

    rmac_pool_kernel<<<BC / 4, 256, 0, stream>>>(x, vt);    // 8192 blocks, 1 wave/tile
    rmac_norm_kernel<<<B_, 512, 0, stream>>>(vt, out);      // 64 blocks
}